// Round 1
// baseline (734.501 us; speedup 1.0000x reference)
//
#include <hip/hip_runtime.h>
#include <cstddef>

// Fused single-head causal attention. B=4096, T=96, C=256, H=64.
// out = softmax(mask((x@Wq)(x@Wk)^T * C^-0.5)) @ (x@Wv)
//
// v5: latency-oriented rework of phase 1 + coalesced epilogue.
//  - Phase 1 runs BK=64 (4 K-iterations instead of 8): half the barriers,
//    24 MFMAs per barrier, 24 KB ping-pong pack slices.
//  - Raw s_barrier + counted s_waitcnt vmcnt(N) (T4): depth-2 x prefetch stays
//    in flight ACROSS barriers. v4's __syncthreads drained vmcnt(0) every
//    K-step, putting a full HBM latency on the critical path each iteration
//    (VALUBusy 18.6%, MfmaUtil 7%, HBM 30% — all idle = latency-bound).
//  - Epilogue: oacc bounces through a per-wave LDS tile, stores become
//    4x global_store_dwordx4 covering full 256B rows (v4's scalar-dword
//    epilogue measured WRITE_SIZE 342 MB vs 101 MB of actual output).

typedef __bf16 bf16x8 __attribute__((ext_vector_type(8)));
typedef float f32x4 __attribute__((ext_vector_type(4)));

#define GLOAD_LDS16(gp, lp)                                                     \
  __builtin_amdgcn_global_load_lds(                                             \
      (const __attribute__((address_space(1))) void*)(gp),                      \
      (__attribute__((address_space(3))) void*)(lp), 16, 0, 0)

// compile-time memory fence: raw s_barrier is IntrNoMem in LLVM, so memory ops
// can cross it unless fenced; also pins global_load_lds vs x-load issue order
// so the counted vmcnt(N) waits below stay valid.
#define FENCE() asm volatile("" ::: "memory")
#define WAITVM(N) asm volatile("s_waitcnt vmcnt(" #N ")" ::: "memory")
#define BAR() do { __builtin_amdgcn_s_barrier(); FENCE(); } while (0)

static __device__ __forceinline__ unsigned short f2bf_u16(float f) {
  union { float f; unsigned int u; } c; c.f = f;
  return (unsigned short)((c.u + 0x7FFFu + ((c.u >> 16) & 1u)) >> 16);
}

// ---- weight packing: fp32 [256][64] -> bf16 B-fragment order, kt-major ----
// pack[kt][p][nt][lane][j] = bf16(W_p[32*kt + (lane>>4)*8 + j][16*nt + (lane&15)])
// One kt-slice (3p x 4nt x 64lane x 8) = 12,288 B contiguous. (unchanged)
__global__ void pack_w(const float* __restrict__ Wk, const float* __restrict__ Wq,
                       const float* __restrict__ Wv, unsigned short* __restrict__ pack) {
  int idx = blockIdx.x * blockDim.x + threadIdx.x;  // 6144 total
  if (idx >= 6144) return;
  int lane = idx & 63;
  int t = idx >> 6;          // t = kt*12 + p*4 + nt
  int nt = t & 3;
  int p  = (t >> 2) % 3;
  int kt = t / 12;
  const float* W = (p == 0) ? Wk : (p == 1) ? Wq : Wv;
  int k0 = kt * 32 + (lane >> 4) * 8;
  int n  = nt * 16 + (lane & 15);
  unsigned short* dst = pack + (size_t)idx * 8;
#pragma unroll
  for (int j = 0; j < 8; ++j) dst[j] = f2bf_u16(W[(size_t)(k0 + j) * 64 + n]);
}

// ---------------- fused attention, 2 batches per block ----------------
#define LDK 72    // k buffer row stride (u16)
#define LDP 104   // P / q-scratch row stride (u16)
#define LDV 104   // vT row stride inside recycled k region

__global__ __launch_bounds__(768, 6) void head_fused(
    const float* __restrict__ x, const unsigned short* __restrict__ pack,
    float* __restrict__ out) {
  // One flat LDS arena with phase-based aliasing:
  //   [0, 49152)      : pack ping-pong, 2 x 24576 B        (phase 1 loop only)
  //   [0, 39936)      : SA = q-scratch then P, 2x96xLDP u16 (phase 2/3)
  //   [39936, 67584)  : ks2 = k, then vT, 2x96xLDK u16
  //   [67584, 68352)  : rowsum, 2x96 f32
  //   [0, 49152)      : per-wave O staging tiles, 12 x 4096 B (epilogue)
  __shared__ __attribute__((aligned(16))) unsigned char smem[68352];
  unsigned short* SA  = (unsigned short*)smem;
  unsigned short* ks2 = (unsigned short*)(smem + 39936);
  float*          rsm = (float*)(smem + 67584);

  const int w    = threadIdx.x >> 6;   // 0..11
  const int half = w >= 6;
  const int w6   = w - 6 * half;       // row-tile 0..5
  const int lane = threadIdx.x & 63;
  const int lo   = lane & 15;
  const int hi   = lane >> 4;

  const int bb = 2 * blockIdx.x + half;
  const float* __restrict__ xb = x + (size_t)bb * (96 * 256);

  unsigned short* SAh  = SA  + half * (96 * LDP);
  unsigned short* ks2h = ks2 + half * (96 * LDK);
  float*          rsh  = rsm + half * 96;

  // ---- Phase 1: [k|q|v] = x @ [Wk|Wq|Wv], BK=64 loop, counted-vmcnt dbuf ----
  f32x4 acc[3][4];
#pragma unroll
  for (int p = 0; p < 3; ++p)
#pragma unroll
    for (int nt = 0; nt < 4; ++nt) acc[p][nt] = (f32x4){0.f, 0.f, 0.f, 0.f};

  const int am = 16 * w6 + lo;                       // x row this lane supplies
  const float* xrow = xb + (size_t)am * 256 + hi * 8;

  f32x4 A0[4], A1[4];  // two x prefetch slots (16 floats = one BK=64 chunk each)

#define XLOAD(SL, IT) do {                         \
    const float* xp_ = xrow + (IT) * 64;           \
    SL[0] = *(const f32x4*)(xp_);                  \
    SL[1] = *(const f32x4*)(xp_ + 4);              \
    SL[2] = *(const f32x4*)(xp_ + 32);             \
    SL[3] = *(const f32x4*)(xp_ + 36);             \
  } while (0)

  // stage slices 2*IT, 2*IT+1 (24 KB) into dbuf half at BUFOFS; the trailing
  // fence keeps later x-loads from being issued ahead of these (vmcnt order).
#define STAGE(IT, BUFOFS) do {                                                        \
    const char* g_ = (const char*)pack + (size_t)(2 * (IT)) * 12288                   \
                     + (size_t)threadIdx.x * 16;                                      \
    GLOAD_LDS16(g_,         smem + (BUFOFS) + (size_t)w * 1024);                      \
    GLOAD_LDS16(g_ + 12288, smem + (BUFOFS) + 12288 + (size_t)w * 1024);              \
    FENCE();                                                                          \
  } while (0)

  union bfu { bf16x8 v; unsigned short u[8]; };

  auto conv = [&](const f32x4* SL, bfu& af0_, bfu& af1_) {
#pragma unroll
    for (int j = 0; j < 4; ++j) {
      af0_.u[j]     = f2bf_u16(SL[0][j]);
      af0_.u[4 + j] = f2bf_u16(SL[1][j]);
      af1_.u[j]     = f2bf_u16(SL[2][j]);
      af1_.u[4 + j] = f2bf_u16(SL[3][j]);
    }
  };
  auto mfma24 = [&](int bufofs, bf16x8 af0_, bf16x8 af1_) {
    const unsigned short* pb = (const unsigned short*)(smem + bufofs);
#pragma unroll
    for (int p = 0; p < 3; ++p)
#pragma unroll
      for (int nt = 0; nt < 4; ++nt) {
        bf16x8 b0 = *(const bf16x8*)(pb + ((p * 4 + nt) * 64 + lane) * 8);
        acc[p][nt] = __builtin_amdgcn_mfma_f32_16x16x32_bf16(af0_, b0, acc[p][nt], 0, 0, 0);
      }
    const unsigned short* pb1 = pb + 6144;   // second 12 KB slice (k+32)
#pragma unroll
    for (int p = 0; p < 3; ++p)
#pragma unroll
      for (int nt = 0; nt < 4; ++nt) {
        bf16x8 b1 = *(const bf16x8*)(pb1 + ((p * 4 + nt) * 64 + lane) * 8);
        acc[p][nt] = __builtin_amdgcn_mfma_f32_16x16x32_bf16(af1_, b1, acc[p][nt], 0, 0, 0);
      }
  };

  // prologue: queue = [stage0(2), x0(4), x1(4)]; wait stage0 only.
  STAGE(0, 0);
  XLOAD(A0, 0);
  XLOAD(A1, 1);
  WAITVM(8);
  BAR();

  { // it 0: reads buf0, stages buf1(slices 2,3), prefetches x(2)
    STAGE(1, 24576);
    bfu af0_, af1_; conv(A0, af0_, af1_);
    XLOAD(A0, 2);
    mfma24(0, af0_.v, af1_.v);
    WAITVM(4);          // drains x1 + stage1; x2 stays in flight
    BAR();
  }
  { // it 1: reads buf1, stages buf0(slices 4,5), prefetches x(3)
    STAGE(2, 0);
    bfu af0_, af1_; conv(A1, af0_, af1_);
    XLOAD(A1, 3);
    mfma24(24576, af0_.v, af1_.v);
    WAITVM(4);          // drains x2 + stage2; x3 stays in flight
    BAR();
  }
  { // it 2: reads buf0, stages buf1(slices 6,7)
    STAGE(3, 24576);
    bfu af0_, af1_; conv(A0, af0_, af1_);
    mfma24(0, af0_.v, af1_.v);
    WAITVM(0);          // drains x3 + stage3
    BAR();
  }
  { // it 3: reads buf1, nothing in flight
    bfu af0_, af1_; conv(A1, af0_, af1_);
    mfma24(24576, af0_.v, af1_.v);
    __syncthreads();    // all pack-LDS reads drained before SA/ks2 overwrite
  }

  // D layout: row = 16*w6 + hi*4 + r, col = 16*nt + lo.  acc[0]=k, [1]=q, [2]=v.
  unsigned short vv[16];  // v D-frags, carried in regs to phase 3
#pragma unroll
  for (int nt = 0; nt < 4; ++nt) {
#pragma unroll
    for (int r = 0; r < 4; ++r) {
      int row = 16 * w6 + hi * 4 + r;
      int col = 16 * nt + lo;
      ks2h[row * LDK + col] = f2bf_u16(acc[0][nt][r]);  // k
      SAh [row * LDP + col] = f2bf_u16(acc[1][nt][r]);  // q (scratch in P buf)
      vv[nt * 4 + r] = f2bf_u16(acc[2][nt][r]);         // v stays in regs
    }
  }
  __syncthreads();  // k,q visible

  // ---- Phase 2: S = q k^T / 16, causal mask, row softmax, P -> SA ----
  f32x4 sacc[6];
#pragma unroll
  for (int jt = 0; jt < 6; ++jt) sacc[jt] = (f32x4){0.f, 0.f, 0.f, 0.f};

  bf16x8 qf0 = *(const bf16x8*)(SAh + (16 * w6 + lo) * LDP + hi * 8);
  bf16x8 qf1 = *(const bf16x8*)(SAh + (16 * w6 + lo) * LDP + 32 + hi * 8);
  for (int jt = 0; jt <= w6; ++jt) {   // causal: tiles jt <= w6 only
    bf16x8 kf0 = *(const bf16x8*)(ks2h + (16 * jt + lo) * LDK + hi * 8);
    bf16x8 kf1 = *(const bf16x8*)(ks2h + (16 * jt + lo) * LDK + 32 + hi * 8);
    sacc[jt] = __builtin_amdgcn_mfma_f32_16x16x32_bf16(qf0, kf0, sacc[jt], 0, 0, 0);
    sacc[jt] = __builtin_amdgcn_mfma_f32_16x16x32_bf16(qf1, kf1, sacc[jt], 0, 0, 0);
  }

#pragma unroll
  for (int r = 0; r < 4; ++r) {
    int row = 16 * w6 + hi * 4 + r;
    float pr[6];
    float mx = -1e30f;
    for (int jt = 0; jt <= w6; ++jt) {
      int col = 16 * jt + lo;
      float s = sacc[jt][r] * 0.0625f;           // * C^-0.5
      s = (col <= row) ? s : -1e30f;
      pr[jt] = s;
      mx = fmaxf(mx, s);
    }
#pragma unroll
    for (int off = 1; off < 16; off <<= 1) mx = fmaxf(mx, __shfl_xor(mx, off, 64));
    float sum = 0.f;
    for (int jt = 0; jt <= w6; ++jt) {
      float p = __expf(pr[jt] - mx);
      pr[jt] = p;
      sum += p;
    }
#pragma unroll
    for (int off = 1; off < 16; off <<= 1) sum += __shfl_xor(sum, off, 64);
#pragma unroll
    for (int jt = 0; jt < 6; ++jt) {
      float p = (jt <= w6) ? pr[jt] : 0.f;
      SAh[row * LDP + 16 * jt + lo] = f2bf_u16(p);
    }
    if (lo == 0) rsh[row] = sum;
  }
  __syncthreads();  // all k reads done; P,rowsum visible

  // ---- recycle k buffer as vT ----
  unsigned short* vT = ks2h;  // [64][LDV], 64*104*2 = 13312 B <= 96*72*2
#pragma unroll
  for (int nt = 0; nt < 4; ++nt) {
#pragma unroll
    for (int r = 0; r < 4; ++r) {
      int row = 16 * w6 + hi * 4 + r;
      int col = 16 * nt + lo;
      vT[col * LDV + row] = vv[nt * 4 + r];
    }
  }
  __syncthreads();  // vT visible

  // ---- Phase 3: O = P @ v ----
  f32x4 oacc[4];
#pragma unroll
  for (int nt = 0; nt < 4; ++nt) oacc[nt] = (f32x4){0.f, 0.f, 0.f, 0.f};

  const int ksmax = (16 * w6 + 15) >> 5;  // skip all-zero K-chunks (causal)
  for (int ks = 0; ks <= ksmax; ++ks) {
    bf16x8 pf = *(const bf16x8*)(SAh + (16 * w6 + lo) * LDP + ks * 32 + hi * 8);
#pragma unroll
    for (int nt = 0; nt < 4; ++nt) {
      bf16x8 vf = *(const bf16x8*)(vT + (16 * nt + lo) * LDV + ks * 32 + hi * 8);
      oacc[nt] = __builtin_amdgcn_mfma_f32_16x16x32_bf16(pf, vf, oacc[nt], 0, 0, 0);
    }
  }

  // ---- epilogue: normalize, per-wave LDS tile, full-row dwordx4 stores ----
  __syncthreads();  // all P/vT reads complete; arena reusable for O tiles
  float* ot = (float*)(smem + (size_t)w * 4096);   // wave-private [16][64] f32
#pragma unroll
  for (int r = 0; r < 4; ++r) {
    float inv = 1.0f / rsh[16 * w6 + hi * 4 + r];
#pragma unroll
    for (int nt = 0; nt < 4; ++nt)
      ot[(hi * 4 + r) * 64 + 16 * nt + lo] = oacc[nt][r] * inv;
  }
  // wave-private tile: no barrier needed between write and read-back.
  float* __restrict__ ob = out + (size_t)bb * (96 * 64);
#pragma unroll
  for (int i = 0; i < 4; ++i) {
    f32x4 o4 = *(const f32x4*)(ot + (i * 4 + hi) * 64 + lo * 4);
    *(f32x4*)(ob + (size_t)(16 * w6 + i * 4 + hi) * 64 + lo * 4) = o4;
  }
}

extern "C" void kernel_launch(void* const* d_in, const int* in_sizes, int n_in,
                              void* d_out, int out_size, void* d_ws, size_t ws_size,
                              hipStream_t stream) {
  const float* x  = (const float*)d_in[0];
  const float* Wk = (const float*)d_in[1];
  const float* Wq = (const float*)d_in[2];
  const float* Wv = (const float*)d_in[3];
  float* out = (float*)d_out;
  unsigned short* pack = (unsigned short*)d_ws;  // 96 KB, kt-major slices

  const int B = in_sizes[0] / (96 * 256);

  pack_w<<<24, 256, 0, stream>>>(Wk, Wq, Wv, pack);
  head_fused<<<B / 2, 768, 0, stream>>>(x, pack, out);
}

// Round 2
// 567.870 us; speedup vs baseline: 1.2934x; 1.2934x over previous
//
#include <hip/hip_runtime.h>
#include <cstddef>

// Fused single-head causal attention. B=4096, T=96, C=256, H=64.
// out = softmax(mask((x@Wq)(x@Wk)^T * C^-0.5)) @ (x@Wv)
//
// v6: scratch elimination. v4/v5's phase-2 `sacc[6]`/`pr[6]` were indexed by a
// runtime-bounded loop (jt <= w6) -> allocated in scratch -> every QK^T MFMA
// did a local-memory RMW (WRITE_SIZE 342-659 MB vs 101 MB of output, and the
// latency-bound counter signature: MfmaUtil 5-7%, VALUBusy 14-18%, HBM <45%).
// Phase 2 is now fully statically unrolled: MFMAs behind a wave-uniform
// `if (jt <= w6)`, softmax computed uniformly over all 6 tiles (the causal
// mask already yields exp(-1e30)=0 for jt > w6, sacc is zero-init there).
// Phase 1 reverts to v4's low-VGPR BK=32 shape (fits the 80-reg cap from
// __launch_bounds__(768,6)) but keeps raw-barrier + counted s_waitcnt vmcnt(2)
// so the x prefetch stays in flight across the barrier. Epilogue keeps v5's
// per-wave LDS bounce + global_store_dwordx4 full-row stores.

typedef __bf16 bf16x8 __attribute__((ext_vector_type(8)));
typedef float f32x4 __attribute__((ext_vector_type(4)));

#define GLOAD_LDS16(gp, lp)                                                     \
  __builtin_amdgcn_global_load_lds(                                             \
      (const __attribute__((address_space(1))) void*)(gp),                      \
      (__attribute__((address_space(3))) void*)(lp), 16, 0, 0)

// compile-time memory fence: pins issue order of global_load_lds vs x-loads so
// counted vmcnt(N) below is valid; raw s_barrier is IntrNoMem so it needs the
// clobber to stop memory ops crossing it.
#define FENCE() asm volatile("" ::: "memory")
#define WAITVM(N) asm volatile("s_waitcnt vmcnt(" #N ")" ::: "memory")
#define BAR() do { __builtin_amdgcn_s_barrier(); FENCE(); } while (0)

static __device__ __forceinline__ unsigned short f2bf_u16(float f) {
  union { float f; unsigned int u; } c; c.f = f;
  return (unsigned short)((c.u + 0x7FFFu + ((c.u >> 16) & 1u)) >> 16);
}

// ---- weight packing: fp32 [256][64] -> bf16 B-fragment order, kt-major ----
// pack[kt][p][nt][lane][j] = bf16(W_p[32*kt + (lane>>4)*8 + j][16*nt + (lane&15)])
// One kt-slice (3p x 4nt x 64lane x 8) = 12,288 B contiguous.
__global__ void pack_w(const float* __restrict__ Wk, const float* __restrict__ Wq,
                       const float* __restrict__ Wv, unsigned short* __restrict__ pack) {
  int idx = blockIdx.x * blockDim.x + threadIdx.x;  // 6144 total
  if (idx >= 6144) return;
  int lane = idx & 63;
  int t = idx >> 6;          // t = kt*12 + p*4 + nt
  int nt = t & 3;
  int p  = (t >> 2) % 3;
  int kt = t / 12;
  const float* W = (p == 0) ? Wk : (p == 1) ? Wq : Wv;
  int k0 = kt * 32 + (lane >> 4) * 8;
  int n  = nt * 16 + (lane & 15);
  unsigned short* dst = pack + (size_t)idx * 8;
#pragma unroll
  for (int j = 0; j < 8; ++j) dst[j] = f2bf_u16(W[(size_t)(k0 + j) * 64 + n]);
}

// ---------------- fused attention, 2 batches per block ----------------
#define LDK 72    // k buffer row stride (u16)
#define LDP 104   // P / q-scratch row stride (u16)
#define LDV 104   // vT row stride inside recycled k region

__global__ __launch_bounds__(768, 6) void head_fused(
    const float* __restrict__ x, const unsigned short* __restrict__ pack,
    float* __restrict__ out) {
  // One flat LDS arena with phase-based aliasing:
  //   [0, 24576)      : pack ping-pong, 2 x 12288 B        (phase 1 only)
  //   [0, 39936)      : SA = q-scratch then P, 2x96xLDP u16 (phase 2/3)
  //   [39936, 67584)  : ks2 = k, then vT, 2x96xLDK u16
  //   [67584, 68352)  : rowsum, 2x96 f32
  //   [0, 49152)      : per-wave O staging tiles, 12 x 4096 B (epilogue)
  __shared__ __attribute__((aligned(16))) unsigned char smem[68352];
  unsigned short* SA  = (unsigned short*)smem;
  unsigned short* ks2 = (unsigned short*)(smem + 39936);
  float*          rsm = (float*)(smem + 67584);

  const int w    = threadIdx.x >> 6;   // 0..11
  const int half = w >= 6;
  const int w6   = w - 6 * half;       // row-tile 0..5
  const int lane = threadIdx.x & 63;
  const int lo   = lane & 15;
  const int hi   = lane >> 4;

  const int bb = 2 * blockIdx.x + half;
  const float* __restrict__ xb = x + (size_t)bb * (96 * 256);

  unsigned short* SAh  = SA  + half * (96 * LDP);
  unsigned short* ks2h = ks2 + half * (96 * LDK);
  float*          rsh  = rsm + half * 96;

  // ---- Phase 1: [k|q|v] = x @ [Wk|Wq|Wv], BK=32 loop, counted-vmcnt dbuf ----
  f32x4 acc[3][4];
#pragma unroll
  for (int p = 0; p < 3; ++p)
#pragma unroll
    for (int nt = 0; nt < 4; ++nt) acc[p][nt] = (f32x4){0.f, 0.f, 0.f, 0.f};

  const int am = 16 * w6 + lo;                       // x row this lane supplies
  const float* xrow = xb + (size_t)am * 256 + hi * 8;

  // prologue: stage kt=0 slice, issue x(0); wait stage only (x stays in flight)
  GLOAD_LDS16((const char*)pack + (size_t)threadIdx.x * 16,
              smem + (size_t)w * 1024);
  FENCE();
  f32x4 a0 = *(const f32x4*)(xrow);
  f32x4 a1 = *(const f32x4*)(xrow + 4);
  WAITVM(2);
  BAR();

  for (int kt = 0; kt < 7; ++kt) {
    const int cur = kt & 1;
    // stage slice kt+1 (readers of that buffer drained at previous barrier),
    // then prefetch x(kt+1); FENCE keeps stage oldest in the vmcnt queue.
    GLOAD_LDS16((const char*)pack + (size_t)(kt + 1) * 12288 + (size_t)threadIdx.x * 16,
                smem + (size_t)(1 - cur) * 12288 + (size_t)w * 1024);
    FENCE();
    f32x4 na0 = *(const f32x4*)(xrow + (kt + 1) * 32);
    f32x4 na1 = *(const f32x4*)(xrow + (kt + 1) * 32 + 4);

    union { bf16x8 v; unsigned short u[8]; } af;
#pragma unroll
    for (int j = 0; j < 4; ++j) { af.u[j] = f2bf_u16(a0[j]); af.u[4 + j] = f2bf_u16(a1[j]); }
    const unsigned short* pb = (const unsigned short*)(smem + cur * 12288);
#pragma unroll
    for (int p = 0; p < 3; ++p)
#pragma unroll
      for (int nt = 0; nt < 4; ++nt) {
        bf16x8 bf = *(const bf16x8*)(pb + ((p * 4 + nt) * 64 + lane) * 8);
        acc[p][nt] = __builtin_amdgcn_mfma_f32_16x16x32_bf16(af.v, bf, acc[p][nt], 0, 0, 0);
      }
    a0 = na0; a1 = na1;
    WAITVM(2);   // drain stage(kt+1); x(kt+1) stays in flight across barrier
    BAR();
  }
  { // tail kt=7: reads buf1, nothing left in flight after conv
    union { bf16x8 v; unsigned short u[8]; } af;
#pragma unroll
    for (int j = 0; j < 4; ++j) { af.u[j] = f2bf_u16(a0[j]); af.u[4 + j] = f2bf_u16(a1[j]); }
    const unsigned short* pb = (const unsigned short*)(smem + 12288);
#pragma unroll
    for (int p = 0; p < 3; ++p)
#pragma unroll
      for (int nt = 0; nt < 4; ++nt) {
        bf16x8 bf = *(const bf16x8*)(pb + ((p * 4 + nt) * 64 + lane) * 8);
        acc[p][nt] = __builtin_amdgcn_mfma_f32_16x16x32_bf16(af.v, bf, acc[p][nt], 0, 0, 0);
      }
    __syncthreads();   // all pack-LDS reads drained before SA/ks2 overwrite
  }

  // D layout: row = 16*w6 + hi*4 + r, col = 16*nt + lo.  acc[0]=k, [1]=q, [2]=v.
  unsigned short vv[16];  // v D-frags, carried in regs to phase 3 (static idx)
#pragma unroll
  for (int nt = 0; nt < 4; ++nt) {
#pragma unroll
    for (int r = 0; r < 4; ++r) {
      int row = 16 * w6 + hi * 4 + r;
      int col = 16 * nt + lo;
      ks2h[row * LDK + col] = f2bf_u16(acc[0][nt][r]);  // k
      SAh [row * LDP + col] = f2bf_u16(acc[1][nt][r]);  // q (scratch in P buf)
      vv[nt * 4 + r] = f2bf_u16(acc[2][nt][r]);         // v stays in regs
    }
  }
  __syncthreads();  // k,q visible

  // ---- Phase 2: S = q k^T / 16, causal mask, row softmax, P -> SA ----
  // Fully static unroll: sacc/pr must stay in VGPRs (runtime-indexed arrays
  // go to scratch -> this was v4/v5's 250-550 MB of excess HBM traffic).
  f32x4 sacc[6];
#pragma unroll
  for (int jt = 0; jt < 6; ++jt) sacc[jt] = (f32x4){0.f, 0.f, 0.f, 0.f};

  bf16x8 qf0 = *(const bf16x8*)(SAh + (16 * w6 + lo) * LDP + hi * 8);
  bf16x8 qf1 = *(const bf16x8*)(SAh + (16 * w6 + lo) * LDP + 32 + hi * 8);
#pragma unroll
  for (int jt = 0; jt < 6; ++jt) {
    if (jt <= w6) {   // wave-uniform branch; indices stay compile-time
      bf16x8 kf0 = *(const bf16x8*)(ks2h + (16 * jt + lo) * LDK + hi * 8);
      bf16x8 kf1 = *(const bf16x8*)(ks2h + (16 * jt + lo) * LDK + 32 + hi * 8);
      sacc[jt] = __builtin_amdgcn_mfma_f32_16x16x32_bf16(qf0, kf0, sacc[jt], 0, 0, 0);
      sacc[jt] = __builtin_amdgcn_mfma_f32_16x16x32_bf16(qf1, kf1, sacc[jt], 0, 0, 0);
    }
  }

  // Uniform softmax over all 6 tiles: for jt > w6, col > row always, so the
  // causal mask gives -1e30 -> exp -> 0 (sacc there is the zero init).
#pragma unroll
  for (int r = 0; r < 4; ++r) {
    int row = 16 * w6 + hi * 4 + r;
    float pr[6];
    float mx = -1e30f;
#pragma unroll
    for (int jt = 0; jt < 6; ++jt) {
      int col = 16 * jt + lo;
      float s = sacc[jt][r] * 0.0625f;           // * C^-0.5
      s = (col <= row) ? s : -1e30f;
      pr[jt] = s;
      mx = fmaxf(mx, s);
    }
#pragma unroll
    for (int off = 1; off < 16; off <<= 1) mx = fmaxf(mx, __shfl_xor(mx, off, 64));
    float sum = 0.f;
#pragma unroll
    for (int jt = 0; jt < 6; ++jt) {
      float p = __expf(pr[jt] - mx);
      pr[jt] = p;
      sum += p;
    }
#pragma unroll
    for (int off = 1; off < 16; off <<= 1) sum += __shfl_xor(sum, off, 64);
#pragma unroll
    for (int jt = 0; jt < 6; ++jt)
      SAh[row * LDP + 16 * jt + lo] = f2bf_u16(pr[jt]);
    if (lo == 0) rsh[row] = sum;
  }
  __syncthreads();  // all k reads done; P,rowsum visible

  // ---- recycle k buffer as vT ----
  unsigned short* vT = ks2h;  // [64][LDV], 64*104 u16 fits in 96*72 u16
#pragma unroll
  for (int nt = 0; nt < 4; ++nt) {
#pragma unroll
    for (int r = 0; r < 4; ++r) {
      int row = 16 * w6 + hi * 4 + r;
      int col = 16 * nt + lo;
      vT[col * LDV + row] = vv[nt * 4 + r];
    }
  }
  __syncthreads();  // vT visible

  // ---- Phase 3: O = P @ v ----
  f32x4 oacc[4];
#pragma unroll
  for (int nt = 0; nt < 4; ++nt) oacc[nt] = (f32x4){0.f, 0.f, 0.f, 0.f};

  const int ksmax = (16 * w6 + 15) >> 5;  // skip all-zero K-chunks (causal)
  for (int ks = 0; ks <= ksmax; ++ks) {   // oacc indices static -> regs
    bf16x8 pf = *(const bf16x8*)(SAh + (16 * w6 + lo) * LDP + ks * 32 + hi * 8);
#pragma unroll
    for (int nt = 0; nt < 4; ++nt) {
      bf16x8 vf = *(const bf16x8*)(vT + (16 * nt + lo) * LDV + ks * 32 + hi * 8);
      oacc[nt] = __builtin_amdgcn_mfma_f32_16x16x32_bf16(pf, vf, oacc[nt], 0, 0, 0);
    }
  }

  // ---- epilogue: normalize, per-wave LDS tile, full-row dwordx4 stores ----
  __syncthreads();  // all P/vT reads complete; arena reusable for O tiles
  float* ot = (float*)(smem + (size_t)w * 4096);   // wave-private [16][64] f32
#pragma unroll
  for (int r = 0; r < 4; ++r) {
    float inv = 1.0f / rsh[16 * w6 + hi * 4 + r];
#pragma unroll
    for (int nt = 0; nt < 4; ++nt)
      ot[(hi * 4 + r) * 64 + 16 * nt + lo] = oacc[nt][r] * inv;
  }
  // wave-private tile: no barrier needed between write and read-back.
  float* __restrict__ ob = out + (size_t)bb * (96 * 64);
#pragma unroll
  for (int i = 0; i < 4; ++i) {
    f32x4 o4 = *(const f32x4*)(ot + (i * 4 + hi) * 64 + lo * 4);
    *(f32x4*)(ob + (size_t)(16 * w6 + i * 4 + hi) * 64 + lo * 4) = o4;
  }
}

extern "C" void kernel_launch(void* const* d_in, const int* in_sizes, int n_in,
                              void* d_out, int out_size, void* d_ws, size_t ws_size,
                              hipStream_t stream) {
  const float* x  = (const float*)d_in[0];
  const float* Wk = (const float*)d_in[1];
  const float* Wq = (const float*)d_in[2];
  const float* Wv = (const float*)d_in[3];
  float* out = (float*)d_out;
  unsigned short* pack = (unsigned short*)d_ws;  // 96 KB, kt-major slices

  const int B = in_sizes[0] / (96 * 256);

  pack_w<<<24, 256, 0, stream>>>(Wk, Wq, Wv, pack);
  head_fused<<<B / 2, 768, 0, stream>>>(x, pack, out);
}